// Round 3
// baseline (1258.421 us; speedup 1.0000x reference)
//
#include <hip/hip_runtime.h>
#include <hip/hip_bf16.h>
#include <math.h>

// GraphLSTM (binary TreeLSTM), 64 trees x 2047 nodes, H=E=256, C=104.
// Round 2: occupancy fix. p-split GEMM1 (halved accumulators), no hch LDS
// (GEMM2 A-frags direct from global; Hsum from global pair loads), c_in kept
// in registers and exchanged via g-lane shuffles, one barrier per block,
// rcp-based activations, launch_bounds(512,4) -> 2 blocks/CU.

#define NTREES 64
#define TDEPTH 11
#define NPT    2047
#define HD     256
#define H3     768
#define NCLS   104

typedef short v8s __attribute__((ext_vector_type(8)));
typedef float v4f __attribute__((ext_vector_type(4)));
typedef unsigned short u16;
typedef unsigned int   u32;

__device__ __forceinline__ float bfLo(u32 u) {
    return __builtin_bit_cast(float, u << 16);
}
__device__ __forceinline__ float bfHi(u32 u) {
    return __builtin_bit_cast(float, u & 0xffff0000u);
}
__device__ __forceinline__ u16 f2bf(float f) {
    return __builtin_bit_cast(u16, __float2bfloat16(f));
}
__device__ __forceinline__ u32 pk2(float lo, float hi) {
    return (u32)f2bf(lo) | ((u32)f2bf(hi) << 16);
}
__device__ __forceinline__ float sigm_(float x) {
    return __builtin_amdgcn_rcpf(1.0f + __expf(-x));
}
__device__ __forceinline__ float tanh_(float x) {
    // 1 - 2/(e^{2x}+1); x=+inf -> 1, x=-inf -> -1, no NaN.
    return 1.0f - 2.0f * __builtin_amdgcn_rcpf(__expf(2.0f * x) + 1.0f);
}

// Wcat[n][0:256]=W_iou[n][:], Wcat[n][256:512]=U_iou[n][:]  (bf16 row-major
// by output index n). Uf[256][256] bf16.
__global__ __launch_bounds__(256) void prep_weights(
    const float* __restrict__ W_iou, const float* __restrict__ U_iou,
    const float* __restrict__ U_f_w,
    u16* __restrict__ Wcat, u16* __restrict__ Uf)
{
    int tid = blockIdx.x * 256 + threadIdx.x;   // 0..196607
    int n  = tid >> 8;
    int c0 = (tid & 255) * 2;
    float a, b;
    if (c0 < 256) { a = W_iou[n * 256 + c0];       b = W_iou[n * 256 + c0 + 1]; }
    else          { a = U_iou[n * 256 + c0 - 256]; b = U_iou[n * 256 + c0 - 255]; }
    *(u32*)&Wcat[n * 512 + c0] = pk2(a, b);
    if (tid < 32768) {
        int jj = tid >> 7, cc = (tid & 127) * 2;
        *(u32*)&Uf[jj * 256 + cc] = pk2(U_f_w[jj * 256 + cc], U_f_w[jj * 256 + cc + 1]);
    }
}

// One level. 512 threads = 8 waves. Block covers 64 nodes (m0..m0+63).
// GEMM1 (p-split): [64, 768] = Xcat[64, 512] @ Wcat^T  (leaf: K=256)
// GEMM2: [128, 256] = h_prev_children @ Uf^T, A-frags straight from global.
template<bool LEAF>
__global__ __launch_bounds__(512, 4) void level_kernel(
    const int* __restrict__ feat, const float* __restrict__ emb,
    const u16* __restrict__ Wcat, const u16* __restrict__ Uf,
    const float* __restrict__ b_iou, const float* __restrict__ U_f_b,
    const u16* __restrict__ h_prev, const float* __restrict__ c_prev,
    u16* __restrict__ h_cur, float* __restrict__ c_cur,
    float* __restrict__ hsum, int level)
{
    constexpr int XS = LEAF ? 264 : 520;     // xcat row stride (bf16 elems)
    __shared__ u16 xcat[64 * XS];

    const int tid = threadIdx.x;
    const int wv  = tid >> 6;       // wave 0..7
    const int ln  = tid & 63;
    const int g   = ln >> 4;        // lane group 0..3
    const int r15 = ln & 15;
    const int m0  = blockIdx.x * 64;
    const int L   = 1 << level;

    // ---- stage X = bf16(emb[features]) : wave w stages rows 8w..8w+7 ----
    int fidx[8];
    #pragma unroll
    for (int it = 0; it < 8; ++it) {
        const int m    = m0 + wv * 8 + it;
        const int tree = m >> level;
        const int pos  = m & (L - 1);
        fidx[it] = feat[tree * NPT + (L - 1) + pos];
    }
    #pragma unroll
    for (int it = 0; it < 8; ++it) {
        const int r = wv * 8 + it;
        const float4 v = *(const float4*)(emb + (size_t)fidx[it] * HD + ln * 4);
        uint2 o;
        o.x = pk2(v.x, v.y);
        o.y = pk2(v.z, v.w);
        *(uint2*)&xcat[r * XS + ln * 4] = o;
    }

    // ---- stage Hsum = bf16(h_l + h_r) into xcat[:,256:512] (from global) ----
    if constexpr (!LEAF) {
        #pragma unroll
        for (int it = 0; it < 8; ++it) {
            const int r = wv * 8 + it;
            const int m = m0 + r;
            const uint2 a = *(const uint2*)(h_prev + (size_t)(2 * m) * HD + ln * 4);
            const uint2 b = *(const uint2*)(h_prev + (size_t)(2 * m + 1) * HD + ln * 4);
            uint2 o;
            o.x = pk2(bfLo(a.x) + bfLo(b.x), bfHi(a.x) + bfHi(b.x));
            o.y = pk2(bfLo(a.y) + bfLo(b.y), bfHi(a.y) + bfHi(b.y));
            *(uint2*)&xcat[r * XS + 256 + ln * 4] = o;
        }
    }
    __syncthreads();   // the only block barrier

    // ---- GEMM2: forget preactivations, A-frags from global h_prev ----
    // cinreg[nt][mt][q]: c_in for node 8*mt+2*g+q, channel 16*(wv+8*nt)+r15.
    float cinreg[2][8][2];
    if constexpr (!LEAF) {
        const u16* hbase = h_prev + (size_t)(2 * m0) * HD;
        #pragma unroll
        for (int nt = 0; nt < 2; ++nt) {
            v4f acc2[8];
            #pragma unroll
            for (int mt = 0; mt < 8; ++mt) acc2[mt] = (v4f){0.f, 0.f, 0.f, 0.f};
            const int n2 = wv + 8 * nt;
            for (int ks = 0; ks < 8; ++ks) {
                v8s a2[8];
                #pragma unroll
                for (int mt = 0; mt < 8; ++mt)
                    a2[mt] = *(const v8s*)(hbase + (size_t)(16 * mt + r15) * HD + ks * 32 + g * 8);
                const v8s b = *(const v8s*)(Uf + (size_t)(16 * n2 + r15) * HD + ks * 32 + g * 8);
                #pragma unroll
                for (int mt = 0; mt < 8; ++mt)
                    acc2[mt] = __builtin_amdgcn_mfma_f32_16x16x32_bf16(a2[mt], b, acc2[mt], 0, 0, 0);
            }
            const int ch = 16 * n2 + r15;
            const float fb = U_f_b[ch];
            #pragma unroll
            for (int mt = 0; mt < 8; ++mt) {
                #pragma unroll
                for (int q = 0; q < 2; ++q) {
                    const int cr0 = 16 * mt + 4 * g + 2 * q;
                    const float f0 = sigm_(acc2[mt][2 * q] + fb);
                    const float f1 = sigm_(acc2[mt][2 * q + 1] + fb);
                    const float c0 = c_prev[(size_t)(2 * m0 + cr0) * HD + ch];
                    const float c1 = c_prev[(size_t)(2 * m0 + cr0 + 1) * HD + ch];
                    cinreg[nt][mt][q] = fmaf(f0, c0, f1 * c1);
                }
            }
        }
    }

    // ---- GEMM1 (p-split) + fused epilogue ----
    #pragma unroll
    for (int p = 0; p < 2; ++p) {
        v4f acc1[3][4];
        #pragma unroll
        for (int t = 0; t < 3; ++t)
            #pragma unroll
            for (int mt = 0; mt < 4; ++mt)
                acc1[t][mt] = (v4f){0.f, 0.f, 0.f, 0.f};

        constexpr int KS1 = LEAF ? 8 : 16;
        for (int ks = 0; ks < KS1; ++ks) {
            v8s a1[4];
            #pragma unroll
            for (int mt = 0; mt < 4; ++mt)
                a1[mt] = *(const v8s*)&xcat[(16 * mt + r15) * XS + ks * 32 + g * 8];
            #pragma unroll
            for (int t = 0; t < 3; ++t) {
                const int n = wv + 8 * p + 16 * t;   // i / o / u panel
                const v8s b = *(const v8s*)(Wcat + (size_t)(16 * n + r15) * 512 + ks * 32 + g * 8);
                #pragma unroll
                for (int mt = 0; mt < 4; ++mt)
                    acc1[t][mt] = __builtin_amdgcn_mfma_f32_16x16x32_bf16(a1[mt], b, acc1[t][mt], 0, 0, 0);
            }
        }

        const int ch = 16 * (wv + 8 * p) + r15;
        const float bi = b_iou[ch];
        const float bo = b_iou[256 + ch];
        const float bu = b_iou[512 + ch];
        float hacc = 0.f;
        #pragma unroll
        for (int mt = 0; mt < 4; ++mt) {
            #pragma unroll
            for (int r = 0; r < 4; ++r) {
                const int ml = 16 * mt + 4 * g + r;
                const float iv = sigm_(acc1[0][mt][r] + bi);
                const float ov = sigm_(acc1[1][mt][r] + bo);
                const float uv = tanh_(acc1[2][mt][r] + bu);
                float ci = 0.f;
                if constexpr (!LEAF) {
                    // pull c_in from the g-lane that holds node ml's value
                    const int src = (((4 * g + r) & 7) >> 1) * 16 + r15;
                    const float va = __shfl(cinreg[p][2 * mt][r & 1], src, 64);
                    const float vb = __shfl(cinreg[p][2 * mt + 1][r & 1], src, 64);
                    ci = (g >= 2) ? vb : va;
                }
                const float cn = fmaf(iv, uv, ci);
                const float hn = ov * tanh_(cn);
                const size_t m = (size_t)(m0 + ml);
                h_cur[m * HD + ch] = f2bf(hn);
                c_cur[m * HD + ch] = cn;
                if (level >= 6) hacc += hn;
                else atomicAdd(&hsum[((m0 + ml) >> level) * HD + ch], hn);
            }
        }
        if (level >= 6) atomicAdd(&hsum[(m0 >> level) * HD + ch], hacc);
    }
}

// out[tree][c] = (hsum[tree]/NPT) . lin_w[c] + lin_b[c]
__global__ __launch_bounds__(128) void final_kernel(
    const float* __restrict__ hsum, const float* __restrict__ lin_w,
    const float* __restrict__ lin_b, float* __restrict__ out)
{
    __shared__ float hg[HD];
    const int tree = blockIdx.x;
    for (int j = threadIdx.x; j < HD; j += 128)
        hg[j] = hsum[tree * HD + j] * (1.0f / (float)NPT);
    __syncthreads();
    const int c = threadIdx.x;
    if (c < NCLS) {
        const float* wr = lin_w + (size_t)c * HD;
        float acc = lin_b[c];
        #pragma unroll 4
        for (int j = 0; j < HD; ++j)
            acc = fmaf(hg[j], wr[j], acc);
        out[tree * NCLS + c] = acc;
    }
}

extern "C" void kernel_launch(void* const* d_in, const int* in_sizes, int n_in,
                              void* d_out, int out_size, void* d_ws, size_t ws_size,
                              hipStream_t stream)
{
    const int*   feat  = (const int*)d_in[0];
    const float* emb   = (const float*)d_in[1];
    const float* W_iou = (const float*)d_in[2];
    const float* U_iou = (const float*)d_in[3];
    const float* b_iou = (const float*)d_in[4];
    const float* U_f_w = (const float*)d_in[5];
    const float* U_f_b = (const float*)d_in[6];
    const float* lin_w = (const float*)d_in[7];
    const float* lin_b = (const float*)d_in[8];
    float* out = (float*)d_out;

    char* ws = (char*)d_ws;
    size_t off = 0;
    auto alloc = [&](size_t bytes) -> void* {
        void* p = ws + off;
        off += (bytes + 255) & ~(size_t)255;
        return p;
    };
    u16*   Wcat = (u16*)alloc((size_t)H3 * 512 * 2);
    u16*   Uf   = (u16*)alloc((size_t)HD * HD * 2);
    float* hsum = (float*)alloc((size_t)NTREES * HD * 4);
    u16*   hA   = (u16*)alloc((size_t)65536 * HD * 2);
    u16*   hB   = (u16*)alloc((size_t)32768 * HD * 2);
    float* cA   = (float*)alloc((size_t)65536 * HD * 4);
    float* cB   = (float*)alloc((size_t)32768 * HD * 4);
    (void)ws_size; (void)in_sizes; (void)n_in; (void)out_size;

    prep_weights<<<768, 256, 0, stream>>>(W_iou, U_iou, U_f_w, Wcat, Uf);
    hipMemsetAsync(hsum, 0, (size_t)NTREES * HD * 4, stream);

    for (int l = TDEPTH - 1; l >= 0; --l) {
        const int blocks = 1 << l;              // (64 << l) / 64
        const int p      = (TDEPTH - 1 - l) & 1;
        u16*   hc = p ? hB : hA;
        float* cc = p ? cB : cA;
        const u16*   hp = p ? hA : hB;
        const float* cp = p ? cA : cB;
        if (l == TDEPTH - 1) {
            level_kernel<true><<<blocks, 512, 0, stream>>>(
                feat, emb, Wcat, Uf, b_iou, U_f_b,
                nullptr, nullptr, hc, cc, hsum, l);
        } else {
            level_kernel<false><<<blocks, 512, 0, stream>>>(
                feat, emb, Wcat, Uf, b_iou, U_f_b,
                hp, cp, hc, cc, hsum, l);
        }
    }

    final_kernel<<<NTREES, 128, 0, stream>>>(hsum, lin_w, lin_b, out);
}